// Round 9
// baseline (115.759 us; speedup 1.0000x reference)
//
#include <hip/hip_runtime.h>
#include <hip/hip_bf16.h>
#include <math.h>

// Problem constants (B=1)
#define TT   512
#define CEMB 768
#define NH   12
#define NKV  6
#define HD   64
#define KVC  (NKV*HD)   // 384

typedef short short8 __attribute__((ext_vector_type(8)));
typedef float floatx4 __attribute__((ext_vector_type(4)));

// fp32 pair -> packed bf16 (round-to-nearest via HW packed convert)
__device__ __forceinline__ unsigned pack_bf16(float lo, float hi){
  __hip_bfloat162 h = __float22bfloat162_rn(make_float2(lo, hi));
  return *reinterpret_cast<unsigned*>(&h);
}
__device__ __forceinline__ unsigned short bf16_rn(float f){
  unsigned u = __float_as_uint(f);
  u += 0x7FFFu + ((u>>16)&1u);
  return (unsigned short)(u>>16);
}
__device__ __forceinline__ float bf16_to_f32(unsigned short u){
  return __uint_as_float(((unsigned)u) << 16);
}

// ============================================================================
// K0: one-shot fragment packing (round-9).
//  bx 0..191   : X (512x768 f32, [row][k]) -> A-fragments XF
//  bx 192..767 : [Wq|Wk|Wv] (f32, [k][n], 1536 cols) -> B-fragments WF
//  bx 768..803 : Wp -> WpF (moved verbatim from old K1 tail blocks)
// Fragment layout (established by K4/WpF idiom):
//   A-frag (row,k): ushort[ ((s*24+ks)*64 + qq*16 + r)*8 + j ]
//     s=row/16, r=row%16, ks=k/32, qq=(k%32)/8, j=k%8
//   B-frag (n,k) per 16-col strip, same formula with r=n%16, strip=(nt*4+c).
// Values identical to old K1's per-step packs (same pack_bf16) -> GEMM
// results bit-identical.
// ============================================================================
__global__ void __launch_bounds__(256) pack_frags(
    const float* __restrict__ X,
    const float* __restrict__ Wq, const float* __restrict__ Wk, const float* __restrict__ Wv,
    const float* __restrict__ Wp,
    unsigned short* __restrict__ XF, unsigned short* __restrict__ WF,
    unsigned short* __restrict__ WpF){
  int bx = blockIdx.x;
  if (bx < 192){
    // X pack: 512 rows x 96 k-groups of 8 consecutive k
    int idx = bx*256 + threadIdx.x;          // 0..49151
    int row = idx / 96, kg = idx - row*96;   // kg 0..95
    const float* src = X + (size_t)row*CEMB + kg*8;
    float4 x0 = *(const float4*)src;
    float4 x1 = *(const float4*)(src+4);
    int s = row>>4, r = row&15, ks = kg>>2, qq = kg&3;
    *(uint4*)&XF[ (((size_t)(s*24 + ks)*64 + qq*16 + r)<<3) ] =
      make_uint4(pack_bf16(x0.x,x0.y), pack_bf16(x0.z,x0.w),
                 pack_bf16(x1.x,x1.y), pack_bf16(x1.z,x1.w));
    return;
  }
  if (bx < 768){
    // W pack: 384 k-pairs x 384 col-groups of 4 over [Wq|Wk|Wv]
    int idx = (bx-192)*256 + threadIdx.x;    // 0..147455
    int kp = idx / 384, n4g = idx - kp*384;
    int kk = kp*2, n = n4g*4;                // n 0..1535 (groups never straddle)
    const float* W; int ldb, col;
    if (n < 768)      { W = Wq; ldb = CEMB; col = n; }
    else if (n < 1152){ W = Wk; ldb = KVC;  col = n-768; }
    else              { W = Wv; ldb = KVC;  col = n-1152; }
    float4 w0 = *(const float4*)&W[(size_t)kk*ldb + col];
    float4 w1 = *(const float4*)&W[(size_t)(kk+1)*ldb + col];
    int ks = kk>>5, qq = (kk>>3)&3, j = kk&7;  // j even
    #pragma unroll
    for(int i=0;i<4;i++){
      int ni = n+i, nt = ni>>6, c = (ni>>4)&3, r = ni&15;
      *(unsigned*)&WF[ (((size_t)((nt*4+c)*24 + ks)*64 + qq*16 + r)<<3) + j ] =
        pack_bf16((&w0.x)[i], (&w1.x)[i]);
    }
    return;
  }
  // Wp pack (verbatim from old K1 tail)
  int t0 = (bx-768)*256 + threadIdx.x;       // 0..9215
  for(int g=0; g<8; ++g){
    int u  = g*9216 + t0;                    // 0..73727
    int kp = u / 192;
    int n4 = (u - kp*192)*4;
    int kk = kp*2;
    float4 w0 = *(const float4*)&Wp[(size_t)kk*CEMB + n4];
    float4 w1 = *(const float4*)&Wp[(size_t)(kk+1)*CEMB + n4];
    int ks = kk>>5, qq = (kk>>3)&3, j = kk&7;  // j even
    #pragma unroll
    for(int i=0;i<4;i++){
      int n = n4+i, ct = n>>4, r = n&15;
      *(unsigned*)&WpF[ (((size_t)(ct*24 + ks)*64 + qq*16 + r)<<3) + j ] =
        pack_bf16((&w0.x)[i], (&w1.x)[i]);
    }
  }
}

// ============================================================================
// K1: QKV GEMM, fragment-direct (round-9 rewrite, K4-clone structure).
// Old K1 was staging-bound: per 32-K step, 12 pack_bf16 + LDS round-trip +
// 2 barriers for only 4 MFMA, and each of 8 row-blocks re-packed the same B.
// Now: zero LDS, zero barriers; 192 blocks (8mt x 24nt of 64 cols); per wave
// 16 rows x 64 cols, 24 ks of {5 x b128 L2 loads + 4 MFMA}, 3-slot rotating
// prefetch (compile-time indices). Same accumulation order as before ->
// q/k/v bit-identical. RoPE/RMS epilogue verbatim (same lane mapping).
// ============================================================================
__global__ void __launch_bounds__(256) gemm_qkv_mfma(
    const unsigned short* __restrict__ XF, const unsigned short* __restrict__ WF,
    const float* __restrict__ cosb, const float* __restrict__ sinb,
    float* __restrict__ q, float* __restrict__ k, float* __restrict__ v){
  int bx = blockIdx.x;           // 0..191
  int mt = bx / 24, nt = bx % 24;
  int tid = threadIdx.x, w = tid>>6, lane = tid&63, qq = lane>>4, r = lane&15;
  int s = mt*4 + w;              // 16-row strip

  const short8* Af = (const short8*)XF + (size_t)s*24*64 + lane;
  const short8* Bf = (const short8*)WF + (size_t)nt*4*24*64 + lane;

  floatx4 acc[4];
  #pragma unroll
  for(int c=0;c<4;c++) acc[c] = (floatx4){0.f,0.f,0.f,0.f};

  short8 ar[3]; short8 br[3][4];
  #pragma unroll
  for(int p=0;p<2;++p){
    ar[p] = Af[(size_t)p*64];
    #pragma unroll
    for(int c=0;c<4;c++) br[p][c] = Bf[(size_t)(c*24 + p)*64];
  }

  #pragma unroll
  for(int ks=0; ks<24; ++ks){
    int cur = ks % 3;
    if (ks + 2 < 24){
      int nx = (ks+2) % 3;
      ar[nx] = Af[(size_t)(ks+2)*64];
      #pragma unroll
      for(int c=0;c<4;c++) br[nx][c] = Bf[(size_t)(c*24 + ks+2)*64];
    }
    #pragma unroll
    for(int c=0;c<4;c++)
      acc[c] = __builtin_amdgcn_mfma_f32_16x16x32_bf16(ar[cur], br[cur][c], acc[c], 0,0,0);
  }

  // epilogue: RoPE pairs d<->d+32 = acc c<->c+2 (same lane); RMS over 16 lanes.
  #pragma unroll
  for(int reg=0; reg<4; ++reg){
    int t = mt*64 + w*16 + qq*4 + reg;
    if (nt < 18){
      float cs0 = cosb[t*32 + r],      sn0 = sinb[t*32 + r];
      float cs1 = cosb[t*32 + 16 + r], sn1 = sinb[t*32 + 16 + r];
      float x0 = acc[0][reg], x1 = acc[1][reg], x2 = acc[2][reg], x3 = acc[3][reg];
      float n0 = x0*cs0 - x2*sn0;
      float n1 = x1*cs1 - x3*sn1;
      float n2 = x2*cs0 + x0*sn0;
      float n3 = x3*cs1 + x1*sn1;
      float ss = n0*n0 + n1*n1 + n2*n2 + n3*n3;
      ss += __shfl_xor(ss,1); ss += __shfl_xor(ss,2);
      ss += __shfl_xor(ss,4); ss += __shfl_xor(ss,8);
      float sc = rsqrtf(ss*(1.0f/64.0f) + 1e-6f);
      float* dst = (nt < 12) ? (q + (size_t)t*CEMB + nt*64)
                             : (k + (size_t)t*KVC + (nt-12)*64);
      dst[r]    = n0*sc; dst[16+r] = n1*sc;
      dst[32+r] = n2*sc; dst[48+r] = n3*sc;
    } else {
      float* dst = v + (size_t)t*KVC + (nt-18)*64;
      dst[r]    = acc[0][reg]; dst[16+r] = acc[1][reg];
      dst[32+r] = acc[2][reg]; dst[48+r] = acc[3][reg];
    }
  }
}

// ============================================================================
// K2: tropical attention, one 64x64 KV-tile per block. (unchanged from R8:
// 256 thr / 4 rows per thread QK, XCD swizzle, __launch_bounds__(256,3),
// unroll-4 dg loop, MFMA PV with bf16 P [row][72] and V^T [n][72].)
// ============================================================================
__global__ void __launch_bounds__(256, 3) attn_tile(const float* __restrict__ qn,
    const float* __restrict__ kn, const float* __restrict__ vr,
    unsigned short* __restrict__ part_acc, float2* __restrict__ part_ml){
  __shared__ float QPsh[64*68];                          // Q f32 (QK phase)
  __shared__ float Ksh[64*64];                           // K f32, XOR-swizzled
  __shared__ __align__(16) unsigned short VT[64*72];     // V^T bf16 [n][k]
  __shared__ __align__(16) unsigned short Pl[64*72];     // P bf16 [row][k]

  // bijective XCD swizzle: bid%8 = resident XCD (dispatch round-robin);
  // give each XCD a contiguous run of 54 linear tiles.
  int bid = blockIdx.x;                 // 0..431
  int lin = (bid & 7)*54 + (bid >> 3);  // bijection on [0,432)
  int h   = lin / 36;
  int idx = lin % 36;
  int qt = 0, rem = idx;
  while (rem > qt){ rem -= (qt+1); ++qt; }
  int ct = rem;                  // 0..qt
  int t0 = ct*64;

  int kvh  = h >> 1;
  int w    = threadIdx.x >> 6;
  int lane = threadIdx.x & 63;
  int lg   = lane >> 4;
  int lc   = lane & 15;

  // stage Q (f32, stride 68) + K (f32, XOR-swizzled cols)
  #pragma unroll
  for(int sub=0; sub<4; ++sub){
    int rr = w*16 + sub*4 + lg;
    int sw = ((lc ^ (rr>>2)) & 15)*4;
    *(float4*)&QPsh[rr*68 + lc*4] =
      *(const float4*)&qn[(size_t)(qt*64+rr)*CEMB + h*HD + lc*4];
    *(float4*)&Ksh[rr*64 + sw] =
      *(const float4*)&kn[(size_t)(t0+rr)*KVC + kvh*HD + lc*4];
  }
  // stage V transposed as bf16: VT[n][k], pack k-pairs (K1 B-staging idiom)
  {
    int kp = threadIdx.x >> 4;          // k-pair base 0..15
    int n4 = (threadIdx.x & 15)*4;
    #pragma unroll
    for(int half=0; half<2; ++half){
      int kk = (kp + half*16)*2;        // 0..62 even
      float4 v0 = *(const float4*)&vr[(size_t)(t0+kk  )*KVC + kvh*HD + n4];
      float4 v1 = *(const float4*)&vr[(size_t)(t0+kk+1)*KVC + kvh*HD + n4];
      #pragma unroll
      for(int i=0;i<4;i++)
        *(unsigned*)&VT[(n4+i)*72 + kk] = pack_bf16((&v0.x)[i], (&v1.x)[i]);
    }
  }
  __syncthreads();

  float s[4][4];
  #pragma unroll
  for(int r=0;r<4;r++)
    #pragma unroll
    for(int c=0;c<4;c++) s[r][c] = -INFINITY;

  #pragma unroll 4
  for(int dg=0; dg<16; ++dg){
    float4 k4[4], q4[4];
    int ksw = ((dg ^ lc)&15)*4;
    #pragma unroll
    for(int c=0;c<4;c++)
      k4[c] = *(const float4*)&Ksh[(lc*4+c)*64 + ksw];
    #pragma unroll
    for(int r=0;r<4;r++)
      q4[r] = *(const float4*)&QPsh[(w*16+lg*4+r)*68 + dg*4];
    #pragma unroll
    for(int r=0;r<4;r++)
      #pragma unroll
      for(int c=0;c<4;c++)
        s[r][c] = fmaxf(s[r][c],
                  fmaxf(fmaxf(q4[r].x + k4[c].x, q4[r].y + k4[c].y),
                        fmaxf(q4[r].z + k4[c].z, q4[r].w + k4[c].w)));
  }

  float mrow[4], lrow[4];
  #pragma unroll
  for(int r=0;r<4;r++){
    int i = qt*64 + w*16 + lg*4 + r;
    #pragma unroll
    for(int c=0;c<4;c++)
      if (t0 + lc*4 + c > i) s[r][c] = -INFINITY;   // causal mask
    float mt = fmaxf(fmaxf(s[r][0],s[r][1]), fmaxf(s[r][2],s[r][3]));
    mt = fmaxf(mt, __shfl_xor(mt,1));
    mt = fmaxf(mt, __shfl_xor(mt,2));
    mt = fmaxf(mt, __shfl_xor(mt,4));
    mt = fmaxf(mt, __shfl_xor(mt,8));
    float p0 = __expf(s[r][0]-mt), p1 = __expf(s[r][1]-mt);
    float p2 = __expf(s[r][2]-mt), p3 = __expf(s[r][3]-mt);
    float ps = p0+p1+p2+p3;
    ps += __shfl_xor(ps,1); ps += __shfl_xor(ps,2);
    ps += __shfl_xor(ps,4); ps += __shfl_xor(ps,8);
    mrow[r] = mt; lrow[r] = ps;
    int row = w*16 + lg*4 + r;
    *(unsigned*)&Pl[row*72 + lc*4]     = pack_bf16(p0,p1);
    *(unsigned*)&Pl[row*72 + lc*4 + 2] = pack_bf16(p2,p3);
    if (lc == 0) part_ml[(h*TT + i)*8 + ct] = make_float2(mrow[r], lrow[r]);
  }
  __builtin_amdgcn_wave_barrier();   // DS in-order per wave; P rows wave-private

  // PV via MFMA: wave w computes output rows w*16..w*16+15, all 64 cols.
  {
    int r_ = lane & 15, qq = lane >> 4;
    floatx4 pacc[4];
    #pragma unroll
    for(int c=0;c<4;c++) pacc[c] = (floatx4){0.f,0.f,0.f,0.f};

    short8 af0 = *(const short8*)&Pl[(w*16+r_)*72 + qq*8];
    short8 af1 = *(const short8*)&Pl[(w*16+r_)*72 + 32 + qq*8];
    #pragma unroll
    for(int c=0;c<4;c++){
      short8 b0 = *(const short8*)&VT[(c*16+r_)*72 + qq*8];
      short8 b1 = *(const short8*)&VT[(c*16+r_)*72 + 32 + qq*8];
      pacc[c] = __builtin_amdgcn_mfma_f32_16x16x32_bf16(af0, b0, pacc[c], 0,0,0);
      pacc[c] = __builtin_amdgcn_mfma_f32_16x16x32_bf16(af1, b1, pacc[c], 0,0,0);
    }

    #pragma unroll
    for(int reg=0; reg<4; ++reg){
      int i = qt*64 + w*16 + qq*4 + reg;
      size_t base = (size_t)((h*TT + i)*8 + ct)*64;
      #pragma unroll
      for(int c=0;c<4;c++)
        part_acc[base + c*16 + r_] = bf16_rn(pacc[c][reg]);
    }
  }
}

// ============================================================================
// K3: merge <=8 bf16 chunk partials per (h,row) -> yF bf16 A-fragments.
// (unchanged)
// ============================================================================
__global__ void __launch_bounds__(256) attn_reduce(const unsigned short* __restrict__ part_acc,
    const float2* __restrict__ part_ml, unsigned short* __restrict__ yF){
  int wid  = (blockIdx.x * blockDim.x + threadIdx.x) >> 6;  // 0..6143
  int lane = threadIdx.x & 63;
  int h = wid >> 9;
  int i = wid & 511;
  int nch = (i >> 6) + 1;       // wave-uniform
  int base = (h*TT + i)*8;

  float2 mls[8]; float acs[8];
  #pragma unroll
  for(int c=0;c<8;c++){
    mls[c] = part_ml[base + c];
    acs[c] = bf16_to_f32(part_acc[(size_t)(base + c)*64 + lane]);
  }

  float m = -INFINITY, l = 0.f, a = 0.f;
  #pragma unroll
  for(int c=0;c<8;c++){
    if (c < nch){
      float m_new = fmaxf(m, mls[c].x);
      float sa  = __expf(m - m_new);
      float sc_ = __expf(mls[c].x - m_new);
      l = l*sa + mls[c].y*sc_;
      a = a*sa + acs[c]*sc_;
      m = m_new;
    }
  }
  float val = a / l;
  int s = i>>4, rr = i&15;
  int ks = h*2 + (lane>>5), q2 = (lane>>3)&3, j = lane&7;
  yF[ (((size_t)(s*24 + ks)*64 + q2*16 + rr)<<3) + j ] = bf16_rn(val);
}

// ============================================================================
// K4: proj GEMM, fragment-direct, 192 blocks (8mt x 24 ntH of 32 cols).
// 4-deep rotating register prefetch, fully unrolled (compile-time indices).
// (unchanged)
// ============================================================================
__global__ void __launch_bounds__(256) gemm_proj_mfma(
    const unsigned short* __restrict__ yF, const unsigned short* __restrict__ WpF,
    float* __restrict__ out){
  int bx = blockIdx.x;           // 0..191
  int mt = bx / 24, ntH = bx % 24;
  int tid = threadIdx.x, w = tid>>6, lane = tid&63, qq = lane>>4, r = lane&15;
  int s = mt*4 + w;   // 16-row strip

  const short8* Af = (const short8*)yF  + (size_t)s*24*64 + lane;
  const short8* Bf = (const short8*)WpF + lane;

  floatx4 acc[2];
  acc[0] = (floatx4){0.f,0.f,0.f,0.f};
  acc[1] = (floatx4){0.f,0.f,0.f,0.f};

  short8 ar[4]; short8 br[4][2];
  #pragma unroll
  for(int j=0;j<3;++j){
    ar[j] = Af[(size_t)j*64];
    #pragma unroll
    for(int c=0;c<2;c++) br[j][c] = Bf[(size_t)((ntH*2+c)*24 + j)*64];
  }

  #pragma unroll
  for(int ks=0; ks<24; ++ks){
    int cur = ks & 3;
    if (ks + 3 < 24){
      int nx = (ks+3) & 3;
      ar[nx] = Af[(size_t)(ks+3)*64];
      #pragma unroll
      for(int c=0;c<2;c++) br[nx][c] = Bf[(size_t)((ntH*2+c)*24 + ks+3)*64];
    }
    #pragma unroll
    for(int c=0;c<2;c++)
      acc[c] = __builtin_amdgcn_mfma_f32_16x16x32_bf16(ar[cur], br[cur][c], acc[c], 0,0,0);
  }

  #pragma unroll
  for(int reg=0; reg<4; ++reg){
    int t = mt*64 + w*16 + qq*4 + reg;
    float* dst = out + (size_t)t*CEMB + ntH*32;
    #pragma unroll
    for(int c=0;c<2;c++)
      dst[c*16 + r] = acc[c][reg];
  }
}

extern "C" void kernel_launch(void* const* d_in, const int* in_sizes, int n_in,
                              void* d_out, int out_size, void* d_ws, size_t ws_size,
                              hipStream_t stream){
  const float* x    = (const float*)d_in[0];
  const float* cosb = (const float*)d_in[1];
  const float* sinb = (const float*)d_in[2];
  const float* Wq   = (const float*)d_in[3];
  const float* Wk   = (const float*)d_in[4];
  const float* Wv   = (const float*)d_in[5];
  const float* Wp   = (const float*)d_in[6];
  float* out = (float*)d_out;

  float* ws        = (float*)d_ws;
  float* q_raw     = ws;                                // 512*768 f32
  float* k_raw     = q_raw + (size_t)TT*CEMB;           // 512*384 f32
  float* v_raw     = k_raw + (size_t)TT*KVC;            // 512*384 f32
  unsigned short* part_acc = (unsigned short*)(v_raw + (size_t)TT*KVC); // 12*512*8*64 bf16
  float2* part_ml  = (float2*)(part_acc + (size_t)NH*TT*8*64);          // 12*512*8
  unsigned short* WpF = (unsigned short*)(part_ml + (size_t)NH*TT*8);   // 48*24*64*8
  unsigned short* yF  = WpF + (size_t)48*24*64*8;       // 32*24*64*8
  unsigned short* XF  = yF  + (size_t)32*24*64*8;       // 32*24*64*8 (A-frags of X)
  unsigned short* WF  = XF  + (size_t)32*24*64*8;       // 96*24*64*8 (B-frags of Wq|Wk|Wv)

  pack_frags    <<<dim3(804),   256, 0, stream>>>(x, Wq, Wk, Wv, Wp, XF, WF, WpF);
  gemm_qkv_mfma <<<dim3(192),   256, 0, stream>>>(XF, WF, cosb, sinb,
                                                  q_raw, k_raw, v_raw);
  attn_tile     <<<dim3(432),   256, 0, stream>>>(q_raw, k_raw, v_raw, part_acc, part_ml);
  attn_reduce   <<<dim3(NH*TT/4), 256, 0, stream>>>(part_acc, part_ml, yF);
  gemm_proj_mfma<<<dim3(192),   256, 0, stream>>>(yF, WpF, out);
}

// Round 10
// 106.024 us; speedup vs baseline: 1.0918x; 1.0918x over previous
//
#include <hip/hip_runtime.h>
#include <hip/hip_bf16.h>
#include <math.h>

// Problem constants (B=1)
#define TT   512
#define CEMB 768
#define NH   12
#define NKV  6
#define HD   64
#define KVC  (NKV*HD)   // 384

typedef short short8 __attribute__((ext_vector_type(8)));
typedef float floatx4 __attribute__((ext_vector_type(4)));

// fp32 pair -> packed bf16 (round-to-nearest via HW packed convert)
__device__ __forceinline__ unsigned pack_bf16(float lo, float hi){
  __hip_bfloat162 h = __float22bfloat162_rn(make_float2(lo, hi));
  return *reinterpret_cast<unsigned*>(&h);
}
__device__ __forceinline__ unsigned short bf16_rn(float f){
  unsigned u = __float_as_uint(f);
  u += 0x7FFFu + ((u>>16)&1u);
  return (unsigned short)(u>>16);
}
__device__ __forceinline__ float bf16_to_f32(unsigned short u){
  return __uint_as_float(((unsigned)u) << 16);
}
// unpack u32 of 2 bf16 (from pack_bf16): low half = first, high half = second
__device__ __forceinline__ float bfp_lo(unsigned u){ return __uint_as_float(u << 16); }
__device__ __forceinline__ float bfp_hi(unsigned u){ return __uint_as_float(u & 0xFFFF0000u); }

// ============================================================================
// K1: QKV GEMM via bf16 MFMA (2-deep reg prefetch) + RoPE/RMS epilogue.
// Grid x: 0..191 = gemm tiles, 192..227 = Wp fragment-pack blocks.
// (R8-proven; R9's pre-pack split REGRESSED — packing must overlap MFMA.)
// ============================================================================
__global__ void __launch_bounds__(256) gemm_qkv_mfma(
    const float* __restrict__ X,
    const float* __restrict__ Wq, const float* __restrict__ Wk, const float* __restrict__ Wv,
    const float* __restrict__ Wp,
    const float* __restrict__ cosb, const float* __restrict__ sinb,
    float* __restrict__ q, float* __restrict__ k, float* __restrict__ v,
    unsigned short* __restrict__ WpF){
  int bx = blockIdx.x;
  if (bx >= 192){
    int t0 = (bx-192)*256 + threadIdx.x;           // 0..9215
    for(int g=0; g<8; ++g){
      int u  = g*9216 + t0;                        // 0..73727
      int kp = u / 192;
      int n4 = (u - kp*192)*4;
      int kk = kp*2;
      float4 w0 = *(const float4*)&Wp[(size_t)kk*CEMB + n4];
      float4 w1 = *(const float4*)&Wp[(size_t)(kk+1)*CEMB + n4];
      int ks = kk>>5, qq = (kk>>3)&3, j = kk&7;    // j even
      #pragma unroll
      for(int i=0;i<4;i++){
        int n = n4+i, ct = n>>4, r = n&15;
        *(unsigned*)&WpF[ (((size_t)(ct*24 + ks)*64 + qq*16 + r)<<3) + j ] =
          pack_bf16((&w0.x)[i], (&w1.x)[i]);
      }
    }
    return;
  }
  int mt = bx / 24, nt = bx % 24;
  const float* W; int ldb, bcol;
  if (nt < 12)      { W = Wq; ldb = CEMB; bcol = nt*64; }
  else if (nt < 18) { W = Wk; ldb = KVC;  bcol = (nt-12)*64; }
  else              { W = Wv; ldb = KVC;  bcol = (nt-18)*64; }

  __shared__ __align__(16) unsigned short Al[2][64][40];
  __shared__ __align__(16) unsigned short Bl[2][64][40];

  int tid = threadIdx.x;
  int am  = tid>>2,  akg = (tid&3)*8;
  int bkp = tid>>4,  bn4 = (tid&15)*4;
  int w = tid>>6, lane = tid&63, qq = lane>>4, r = lane&15;

  floatx4 acc[4];
  #pragma unroll
  for(int c=0;c<4;c++) acc[c] = (floatx4){0.f,0.f,0.f,0.f};

  const float* Ap = X + (size_t)(mt*64 + am)*CEMB + akg;
  const float* Bp = W + (size_t)(2*bkp)*ldb + bcol + bn4;

  float4 a00 = *(const float4*)(Ap);
  float4 a01 = *(const float4*)(Ap + 4);
  float4 b00 = *(const float4*)(Bp);
  float4 b01 = *(const float4*)(Bp + ldb);
  float4 a10 = *(const float4*)(Ap + 32);
  float4 a11 = *(const float4*)(Ap + 36);
  float4 b10 = *(const float4*)(Bp + (size_t)32*ldb);
  float4 b11 = *(const float4*)(Bp + (size_t)33*ldb);

  auto step = [&](int k0, float4& A0, float4& A1, float4& B0, float4& B1,
                  int bufc) {
    unsigned p0 = pack_bf16(A0.x,A0.y), p1 = pack_bf16(A0.z,A0.w);
    unsigned p2 = pack_bf16(A1.x,A1.y), p3 = pack_bf16(A1.z,A1.w);
    *(uint4*)&Al[bufc][am][akg] = make_uint4(p0,p1,p2,p3);
    #pragma unroll
    for(int i=0;i<4;i++)
      *(unsigned*)&Bl[bufc][bn4+i][2*bkp] = pack_bf16((&B0.x)[i], (&B1.x)[i]);
    if (k0 + 64 < CEMB){                 // prefetch 2 steps ahead
      A0 = *(const float4*)(Ap + k0+64);
      A1 = *(const float4*)(Ap + k0+68);
      B0 = *(const float4*)(Bp + (size_t)(k0+64)*ldb);
      B1 = *(const float4*)(Bp + (size_t)(k0+65)*ldb);
    }
    __syncthreads();
    short8 af = *(short8*)&Al[bufc][w*16 + r][qq*8];
    #pragma unroll
    for(int c=0;c<4;c++){
      short8 bfr = *(short8*)&Bl[bufc][c*16 + r][qq*8];
      acc[c] = __builtin_amdgcn_mfma_f32_16x16x32_bf16(af, bfr, acc[c], 0,0,0);
    }
  };

  for(int k0=0; k0<CEMB; k0+=64){
    step(k0,    a00,a01,b00,b01, 0);
    step(k0+32, a10,a11,b10,b11, 1);
  }

  // epilogue: RoPE pairs d<->d+32 = acc c<->c+2 (same lane); RMS over 16 lanes.
  #pragma unroll
  for(int reg=0; reg<4; ++reg){
    int t = mt*64 + w*16 + qq*4 + reg;
    if (nt < 18){
      float cs0 = cosb[t*32 + r],      sn0 = sinb[t*32 + r];
      float cs1 = cosb[t*32 + 16 + r], sn1 = sinb[t*32 + 16 + r];
      float x0 = acc[0][reg], x1 = acc[1][reg], x2 = acc[2][reg], x3 = acc[3][reg];
      float n0 = x0*cs0 - x2*sn0;
      float n1 = x1*cs1 - x3*sn1;
      float n2 = x2*cs0 + x0*sn0;
      float n3 = x3*cs1 + x1*sn1;
      float ss = n0*n0 + n1*n1 + n2*n2 + n3*n3;
      ss += __shfl_xor(ss,1); ss += __shfl_xor(ss,2);
      ss += __shfl_xor(ss,4); ss += __shfl_xor(ss,8);
      float sc = rsqrtf(ss*(1.0f/64.0f) + 1e-6f);
      float* dst = (nt < 12) ? (q + (size_t)t*CEMB + nt*64)
                             : (k + (size_t)t*KVC + (nt-12)*64);
      dst[r]    = n0*sc; dst[16+r] = n1*sc;
      dst[32+r] = n2*sc; dst[48+r] = n3*sc;
    } else {
      float* dst = v + (size_t)t*KVC + (nt-18)*64;
      dst[r]    = acc[0][reg]; dst[16+r] = acc[1][reg];
      dst[32+r] = acc[2][reg]; dst[48+r] = acc[3][reg];
    }
  }
}

// ============================================================================
// K2: tropical attention, one 64x64 KV-tile per block.
// Kept: 256 thr / 4 rows per thread QK, XCD swizzle, MFMA PV (bf16 P/V^T).
// Round-10 change: Q and K stored in LDS as packed-bf16 u32 pairs.
//   LDS 52.2 -> 35.3 KB (Q 8.7K + K 8.2K + VT 9.2K + Pl 9.2K)
//   => 4 blocks/CU; __launch_bounds__(256,4) caps VGPR at 128.
//   dg-loop unroll reduced 4->2 to meet the cap without scratch.
// Swizzle algebra preserved in u32 units (reads broadcast / <=2-way banks).
// Numerics: Q,K bf16-rounded before max-plus (score err ~2^-8); P/V/partials
// already bf16 => expected absmax ~0.008. Revert if >0.02 or fail.
// ============================================================================
__global__ void __launch_bounds__(256, 4) attn_tile(const float* __restrict__ qn,
    const float* __restrict__ kn, const float* __restrict__ vr,
    unsigned short* __restrict__ part_acc, float2* __restrict__ part_ml){
  __shared__ __align__(16) unsigned Qsh[64*34];          // Q bf16-pairs [row][d2]
  __shared__ __align__(16) unsigned Ksh[64*32];          // K bf16-pairs, XOR-swizzled
  __shared__ __align__(16) unsigned short VT[64*72];     // V^T bf16 [n][k]
  __shared__ __align__(16) unsigned short Pl[64*72];     // P bf16 [row][k]

  // bijective XCD swizzle: bid%8 = resident XCD (dispatch round-robin)
  int bid = blockIdx.x;                 // 0..431
  int lin = (bid & 7)*54 + (bid >> 3);  // bijection on [0,432)
  int h   = lin / 36;
  int idx = lin % 36;
  int qt = 0, rem = idx;
  while (rem > qt){ rem -= (qt+1); ++qt; }
  int ct = rem;                  // 0..qt
  int t0 = ct*64;

  int kvh  = h >> 1;
  int w    = threadIdx.x >> 6;
  int lane = threadIdx.x & 63;
  int lg   = lane >> 4;
  int lc   = lane & 15;

  // stage Q + K as packed bf16 (u32 = 2 dims); swizzle group in u32 units
  #pragma unroll
  for(int sub=0; sub<4; ++sub){
    int rr = w*16 + sub*4 + lg;
    float4 qv = *(const float4*)&qn[(size_t)(qt*64+rr)*CEMB + h*HD + lc*4];
    Qsh[rr*34 + lc*2]     = pack_bf16(qv.x, qv.y);
    Qsh[rr*34 + lc*2 + 1] = pack_bf16(qv.z, qv.w);
    int sg = (lc ^ (rr>>2)) & 15;
    float4 kv = *(const float4*)&kn[(size_t)(t0+rr)*KVC + kvh*HD + lc*4];
    Ksh[rr*32 + sg*2]     = pack_bf16(kv.x, kv.y);
    Ksh[rr*32 + sg*2 + 1] = pack_bf16(kv.z, kv.w);
  }
  // stage V transposed as bf16: VT[n][k] (unchanged from R8)
  {
    int kp = threadIdx.x >> 4;          // k-pair base 0..15
    int n4 = (threadIdx.x & 15)*4;
    #pragma unroll
    for(int half=0; half<2; ++half){
      int kk = (kp + half*16)*2;        // 0..62 even
      float4 v0 = *(const float4*)&vr[(size_t)(t0+kk  )*KVC + kvh*HD + n4];
      float4 v1 = *(const float4*)&vr[(size_t)(t0+kk+1)*KVC + kvh*HD + n4];
      #pragma unroll
      for(int i=0;i<4;i++)
        *(unsigned*)&VT[(n4+i)*72 + kk] = pack_bf16((&v0.x)[i], (&v1.x)[i]);
    }
  }
  __syncthreads();

  float s[4][4];
  #pragma unroll
  for(int r=0;r<4;r++)
    #pragma unroll
    for(int c=0;c<4;c++) s[r][c] = -INFINITY;

  #pragma unroll 2
  for(int dg=0; dg<16; ++dg){
    float4 k4[4], q4[4];
    int ksg = (dg ^ lc) & 15;
    #pragma unroll
    for(int c=0;c<4;c++){
      uint2 u = *(const uint2*)&Ksh[(lc*4+c)*32 + ksg*2];
      k4[c] = make_float4(bfp_lo(u.x), bfp_hi(u.x), bfp_lo(u.y), bfp_hi(u.y));
    }
    #pragma unroll
    for(int r=0;r<4;r++){
      uint2 u = *(const uint2*)&Qsh[(w*16+lg*4+r)*34 + dg*2];
      q4[r] = make_float4(bfp_lo(u.x), bfp_hi(u.x), bfp_lo(u.y), bfp_hi(u.y));
    }
    #pragma unroll
    for(int r=0;r<4;r++)
      #pragma unroll
      for(int c=0;c<4;c++)
        s[r][c] = fmaxf(s[r][c],
                  fmaxf(fmaxf(q4[r].x + k4[c].x, q4[r].y + k4[c].y),
                        fmaxf(q4[r].z + k4[c].z, q4[r].w + k4[c].w)));
  }

  float mrow[4], lrow[4];
  #pragma unroll
  for(int r=0;r<4;r++){
    int i = qt*64 + w*16 + lg*4 + r;
    #pragma unroll
    for(int c=0;c<4;c++)
      if (t0 + lc*4 + c > i) s[r][c] = -INFINITY;   // causal mask
    float mt = fmaxf(fmaxf(s[r][0],s[r][1]), fmaxf(s[r][2],s[r][3]));
    mt = fmaxf(mt, __shfl_xor(mt,1));
    mt = fmaxf(mt, __shfl_xor(mt,2));
    mt = fmaxf(mt, __shfl_xor(mt,4));
    mt = fmaxf(mt, __shfl_xor(mt,8));
    float p0 = __expf(s[r][0]-mt), p1 = __expf(s[r][1]-mt);
    float p2 = __expf(s[r][2]-mt), p3 = __expf(s[r][3]-mt);
    float ps = p0+p1+p2+p3;
    ps += __shfl_xor(ps,1); ps += __shfl_xor(ps,2);
    ps += __shfl_xor(ps,4); ps += __shfl_xor(ps,8);
    mrow[r] = mt; lrow[r] = ps;
    int row = w*16 + lg*4 + r;
    *(unsigned*)&Pl[row*72 + lc*4]     = pack_bf16(p0,p1);
    *(unsigned*)&Pl[row*72 + lc*4 + 2] = pack_bf16(p2,p3);
    if (lc == 0) part_ml[(h*TT + i)*8 + ct] = make_float2(mrow[r], lrow[r]);
  }
  __builtin_amdgcn_wave_barrier();   // DS in-order per wave; P rows wave-private

  // PV via MFMA: wave w computes output rows w*16..w*16+15, all 64 cols.
  {
    int r_ = lane & 15, qq = lane >> 4;
    floatx4 pacc[4];
    #pragma unroll
    for(int c=0;c<4;c++) pacc[c] = (floatx4){0.f,0.f,0.f,0.f};

    short8 af0 = *(const short8*)&Pl[(w*16+r_)*72 + qq*8];
    short8 af1 = *(const short8*)&Pl[(w*16+r_)*72 + 32 + qq*8];
    #pragma unroll
    for(int c=0;c<4;c++){
      short8 b0 = *(const short8*)&VT[(c*16+r_)*72 + qq*8];
      short8 b1 = *(const short8*)&VT[(c*16+r_)*72 + 32 + qq*8];
      pacc[c] = __builtin_amdgcn_mfma_f32_16x16x32_bf16(af0, b0, pacc[c], 0,0,0);
      pacc[c] = __builtin_amdgcn_mfma_f32_16x16x32_bf16(af1, b1, pacc[c], 0,0,0);
    }

    #pragma unroll
    for(int reg=0; reg<4; ++reg){
      int i = qt*64 + w*16 + qq*4 + reg;
      size_t base = (size_t)((h*TT + i)*8 + ct)*64;
      #pragma unroll
      for(int c=0;c<4;c++)
        part_acc[base + c*16 + r_] = bf16_rn(pacc[c][reg]);
    }
  }
}

// ============================================================================
// K3: merge <=8 bf16 chunk partials per (h,row) -> yF bf16 A-fragments.
// (unchanged)
// ============================================================================
__global__ void __launch_bounds__(256) attn_reduce(const unsigned short* __restrict__ part_acc,
    const float2* __restrict__ part_ml, unsigned short* __restrict__ yF){
  int wid  = (blockIdx.x * blockDim.x + threadIdx.x) >> 6;  // 0..6143
  int lane = threadIdx.x & 63;
  int h = wid >> 9;
  int i = wid & 511;
  int nch = (i >> 6) + 1;       // wave-uniform
  int base = (h*TT + i)*8;

  float2 mls[8]; float acs[8];
  #pragma unroll
  for(int c=0;c<8;c++){
    mls[c] = part_ml[base + c];
    acs[c] = bf16_to_f32(part_acc[(size_t)(base + c)*64 + lane]);
  }

  float m = -INFINITY, l = 0.f, a = 0.f;
  #pragma unroll
  for(int c=0;c<8;c++){
    if (c < nch){
      float m_new = fmaxf(m, mls[c].x);
      float sa  = __expf(m - m_new);
      float sc_ = __expf(mls[c].x - m_new);
      l = l*sa + mls[c].y*sc_;
      a = a*sa + acs[c]*sc_;
      m = m_new;
    }
  }
  float val = a / l;
  int s = i>>4, rr = i&15;
  int ks = h*2 + (lane>>5), q2 = (lane>>3)&3, j = lane&7;
  yF[ (((size_t)(s*24 + ks)*64 + q2*16 + rr)<<3) + j ] = bf16_rn(val);
}

// ============================================================================
// K4: proj GEMM, fragment-direct, 192 blocks (8mt x 24 ntH of 32 cols).
// 4-deep rotating register prefetch, fully unrolled (compile-time indices).
// (unchanged)
// ============================================================================
__global__ void __launch_bounds__(256) gemm_proj_mfma(
    const unsigned short* __restrict__ yF, const unsigned short* __restrict__ WpF,
    float* __restrict__ out){
  int bx = blockIdx.x;           // 0..191
  int mt = bx / 24, ntH = bx % 24;
  int tid = threadIdx.x, w = tid>>6, lane = tid&63, qq = lane>>4, r = lane&15;
  int s = mt*4 + w;   // 16-row strip

  const short8* Af = (const short8*)yF  + (size_t)s*24*64 + lane;
  const short8* Bf = (const short8*)WpF + lane;

  floatx4 acc[2];
  acc[0] = (floatx4){0.f,0.f,0.f,0.f};
  acc[1] = (floatx4){0.f,0.f,0.f,0.f};

  short8 ar[4]; short8 br[4][2];
  #pragma unroll
  for(int j=0;j<3;++j){
    ar[j] = Af[(size_t)j*64];
    #pragma unroll
    for(int c=0;c<2;c++) br[j][c] = Bf[(size_t)((ntH*2+c)*24 + j)*64];
  }

  #pragma unroll
  for(int ks=0; ks<24; ++ks){
    int cur = ks & 3;
    if (ks + 3 < 24){
      int nx = (ks+3) & 3;
      ar[nx] = Af[(size_t)(ks+3)*64];
      #pragma unroll
      for(int c=0;c<2;c++) br[nx][c] = Bf[(size_t)((ntH*2+c)*24 + ks+3)*64];
    }
    #pragma unroll
    for(int c=0;c<2;c++)
      acc[c] = __builtin_amdgcn_mfma_f32_16x16x32_bf16(ar[cur], br[cur][c], acc[c], 0,0,0);
  }

  #pragma unroll
  for(int reg=0; reg<4; ++reg){
    int t = mt*64 + w*16 + qq*4 + reg;
    float* dst = out + (size_t)t*CEMB + ntH*32;
    #pragma unroll
    for(int c=0;c<2;c++)
      dst[c*16 + r] = acc[c][reg];
  }
}

extern "C" void kernel_launch(void* const* d_in, const int* in_sizes, int n_in,
                              void* d_out, int out_size, void* d_ws, size_t ws_size,
                              hipStream_t stream){
  const float* x    = (const float*)d_in[0];
  const float* cosb = (const float*)d_in[1];
  const float* sinb = (const float*)d_in[2];
  const float* Wq   = (const float*)d_in[3];
  const float* Wk   = (const float*)d_in[4];
  const float* Wv   = (const float*)d_in[5];
  const float* Wp   = (const float*)d_in[6];
  float* out = (float*)d_out;

  float* ws        = (float*)d_ws;
  float* q_raw     = ws;                                // 512*768 f32
  float* k_raw     = q_raw + (size_t)TT*CEMB;           // 512*384 f32
  float* v_raw     = k_raw + (size_t)TT*KVC;            // 512*384 f32
  unsigned short* part_acc = (unsigned short*)(v_raw + (size_t)TT*KVC); // 12*512*8*64 bf16
  float2* part_ml  = (float2*)(part_acc + (size_t)NH*TT*8*64);          // 12*512*8
  unsigned short* WpF = (unsigned short*)(part_ml + (size_t)NH*TT*8);   // 48*24*64*8
  unsigned short* yF  = WpF + (size_t)48*24*64*8;       // 32*24*64*8

  gemm_qkv_mfma <<<dim3(228),   256, 0, stream>>>(x, Wq, Wk, Wv, Wp, cosb, sinb,
                                                  q_raw, k_raw, v_raw, WpF);
  attn_tile     <<<dim3(432),   256, 0, stream>>>(q_raw, k_raw, v_raw, part_acc, part_ml);
  attn_reduce   <<<dim3(NH*TT/4), 256, 0, stream>>>(part_acc, part_ml, yF);
  gemm_proj_mfma<<<dim3(192),   256, 0, stream>>>(yF, WpF, out);
}

// Round 11
// 103.649 us; speedup vs baseline: 1.1168x; 1.0229x over previous
//
#include <hip/hip_runtime.h>
#include <hip/hip_bf16.h>
#include <math.h>

// Problem constants (B=1)
#define TT   512
#define CEMB 768
#define NH   12
#define NKV  6
#define HD   64
#define KVC  (NKV*HD)   // 384

typedef short short8 __attribute__((ext_vector_type(8)));
typedef float floatx4 __attribute__((ext_vector_type(4)));

// fp32 pair -> packed bf16 (round-to-nearest via HW packed convert)
__device__ __forceinline__ unsigned pack_bf16(float lo, float hi){
  __hip_bfloat162 h = __float22bfloat162_rn(make_float2(lo, hi));
  return *reinterpret_cast<unsigned*>(&h);
}
__device__ __forceinline__ unsigned short bf16_rn(float f){
  unsigned u = __float_as_uint(f);
  u += 0x7FFFu + ((u>>16)&1u);
  return (unsigned short)(u>>16);
}
__device__ __forceinline__ float bf16_to_f32(unsigned short u){
  return __uint_as_float(((unsigned)u) << 16);
}

// ============================================================================
// K1: QKV GEMM via bf16 MFMA (2-deep reg prefetch) + RoPE/RMS epilogue.
// Grid x: 0..191 = gemm tiles, 192..227 = Wp fragment-pack blocks.
// Round-11 change (Wp-pack tail only): one thread = one 8-ushort fragment
// row (u = ((ct*24+ks)*4+qq)*16+r) -> uint4 stores fully coalesced (1 KiB
// contiguous per wave-store; was 32 scattered 4B stores/thread), scalar Wp
// column loads line-shared across the 16 consecutive-r lanes. Same
// pack_bf16 of the same pairs to the same addresses -> WpF bit-identical.
// ============================================================================
__global__ void __launch_bounds__(256) gemm_qkv_mfma(
    const float* __restrict__ X,
    const float* __restrict__ Wq, const float* __restrict__ Wk, const float* __restrict__ Wv,
    const float* __restrict__ Wp,
    const float* __restrict__ cosb, const float* __restrict__ sinb,
    float* __restrict__ q, float* __restrict__ k, float* __restrict__ v,
    unsigned short* __restrict__ WpF){
  int bx = blockIdx.x;
  if (bx >= 192){
    int t0 = (bx-192)*256 + threadIdx.x;           // 0..9215
    for(int g=0; g<8; ++g){
      int u  = g*9216 + t0;                        // 0..73727: frag row (ct,ks,qq,r)
      int r  = u & 15;
      int v2 = u >> 4;            // (ct*24+ks)*4 + qq
      int qq = v2 & 3;
      int v3 = v2 >> 2;           // ct*24 + ks
      int ks = v3 % 24;
      int ct = v3 / 24;
      int n  = ct*16 + r;
      int kb = ks*32 + qq*8;
      unsigned p0 = pack_bf16(Wp[(size_t)(kb  )*CEMB + n], Wp[(size_t)(kb+1)*CEMB + n]);
      unsigned p1 = pack_bf16(Wp[(size_t)(kb+2)*CEMB + n], Wp[(size_t)(kb+3)*CEMB + n]);
      unsigned p2 = pack_bf16(Wp[(size_t)(kb+4)*CEMB + n], Wp[(size_t)(kb+5)*CEMB + n]);
      unsigned p3 = pack_bf16(Wp[(size_t)(kb+6)*CEMB + n], Wp[(size_t)(kb+7)*CEMB + n]);
      *(uint4*)&WpF[(size_t)u*8] = make_uint4(p0,p1,p2,p3);
    }
    return;
  }
  int mt = bx / 24, nt = bx % 24;
  const float* W; int ldb, bcol;
  if (nt < 12)      { W = Wq; ldb = CEMB; bcol = nt*64; }
  else if (nt < 18) { W = Wk; ldb = KVC;  bcol = (nt-12)*64; }
  else              { W = Wv; ldb = KVC;  bcol = (nt-18)*64; }

  __shared__ __align__(16) unsigned short Al[2][64][40];
  __shared__ __align__(16) unsigned short Bl[2][64][40];

  int tid = threadIdx.x;
  int am  = tid>>2,  akg = (tid&3)*8;
  int bkp = tid>>4,  bn4 = (tid&15)*4;
  int w = tid>>6, lane = tid&63, qq = lane>>4, r = lane&15;

  floatx4 acc[4];
  #pragma unroll
  for(int c=0;c<4;c++) acc[c] = (floatx4){0.f,0.f,0.f,0.f};

  const float* Ap = X + (size_t)(mt*64 + am)*CEMB + akg;
  const float* Bp = W + (size_t)(2*bkp)*ldb + bcol + bn4;

  float4 a00 = *(const float4*)(Ap);
  float4 a01 = *(const float4*)(Ap + 4);
  float4 b00 = *(const float4*)(Bp);
  float4 b01 = *(const float4*)(Bp + ldb);
  float4 a10 = *(const float4*)(Ap + 32);
  float4 a11 = *(const float4*)(Ap + 36);
  float4 b10 = *(const float4*)(Bp + (size_t)32*ldb);
  float4 b11 = *(const float4*)(Bp + (size_t)33*ldb);

  auto step = [&](int k0, float4& A0, float4& A1, float4& B0, float4& B1,
                  int bufc) {
    unsigned p0 = pack_bf16(A0.x,A0.y), p1 = pack_bf16(A0.z,A0.w);
    unsigned p2 = pack_bf16(A1.x,A1.y), p3 = pack_bf16(A1.z,A1.w);
    *(uint4*)&Al[bufc][am][akg] = make_uint4(p0,p1,p2,p3);
    #pragma unroll
    for(int i=0;i<4;i++)
      *(unsigned*)&Bl[bufc][bn4+i][2*bkp] = pack_bf16((&B0.x)[i], (&B1.x)[i]);
    if (k0 + 64 < CEMB){                 // prefetch 2 steps ahead
      A0 = *(const float4*)(Ap + k0+64);
      A1 = *(const float4*)(Ap + k0+68);
      B0 = *(const float4*)(Bp + (size_t)(k0+64)*ldb);
      B1 = *(const float4*)(Bp + (size_t)(k0+65)*ldb);
    }
    __syncthreads();
    short8 af = *(short8*)&Al[bufc][w*16 + r][qq*8];
    #pragma unroll
    for(int c=0;c<4;c++){
      short8 bfr = *(short8*)&Bl[bufc][c*16 + r][qq*8];
      acc[c] = __builtin_amdgcn_mfma_f32_16x16x32_bf16(af, bfr, acc[c], 0,0,0);
    }
  };

  for(int k0=0; k0<CEMB; k0+=64){
    step(k0,    a00,a01,b00,b01, 0);
    step(k0+32, a10,a11,b10,b11, 1);
  }

  // epilogue: RoPE pairs d<->d+32 = acc c<->c+2 (same lane); RMS over 16 lanes.
  #pragma unroll
  for(int reg=0; reg<4; ++reg){
    int t = mt*64 + w*16 + qq*4 + reg;
    if (nt < 18){
      float cs0 = cosb[t*32 + r],      sn0 = sinb[t*32 + r];
      float cs1 = cosb[t*32 + 16 + r], sn1 = sinb[t*32 + 16 + r];
      float x0 = acc[0][reg], x1 = acc[1][reg], x2 = acc[2][reg], x3 = acc[3][reg];
      float n0 = x0*cs0 - x2*sn0;
      float n1 = x1*cs1 - x3*sn1;
      float n2 = x2*cs0 + x0*sn0;
      float n3 = x3*cs1 + x1*sn1;
      float ss = n0*n0 + n1*n1 + n2*n2 + n3*n3;
      ss += __shfl_xor(ss,1); ss += __shfl_xor(ss,2);
      ss += __shfl_xor(ss,4); ss += __shfl_xor(ss,8);
      float sc = rsqrtf(ss*(1.0f/64.0f) + 1e-6f);
      float* dst = (nt < 12) ? (q + (size_t)t*CEMB + nt*64)
                             : (k + (size_t)t*KVC + (nt-12)*64);
      dst[r]    = n0*sc; dst[16+r] = n1*sc;
      dst[32+r] = n2*sc; dst[48+r] = n3*sc;
    } else {
      float* dst = v + (size_t)t*KVC + (nt-18)*64;
      dst[r]    = acc[0][reg]; dst[16+r] = acc[1][reg];
      dst[32+r] = acc[2][reg]; dst[48+r] = acc[3][reg];
    }
  }
}

// ============================================================================
// K2: tropical attention — R8-proven version restored verbatim (104.8 µs run):
// 256 thr / 4 rows per thread QK (f32 Q/K in LDS), XCD swizzle,
// __launch_bounds__(256,3), unroll-4 dg loop, MFMA PV (bf16 P [row][72],
// V^T [n][72]). R10's bf16-Q/K 4-blocks/CU variant was neutral-to-negative
// (106.0) -> reverted.
// ============================================================================
__global__ void __launch_bounds__(256, 3) attn_tile(const float* __restrict__ qn,
    const float* __restrict__ kn, const float* __restrict__ vr,
    unsigned short* __restrict__ part_acc, float2* __restrict__ part_ml){
  __shared__ float QPsh[64*68];                          // Q f32 (QK phase)
  __shared__ float Ksh[64*64];                           // K f32, XOR-swizzled
  __shared__ __align__(16) unsigned short VT[64*72];     // V^T bf16 [n][k]
  __shared__ __align__(16) unsigned short Pl[64*72];     // P bf16 [row][k]

  // bijective XCD swizzle: bid%8 = resident XCD (dispatch round-robin);
  // give each XCD a contiguous run of 54 linear tiles.
  int bid = blockIdx.x;                 // 0..431
  int lin = (bid & 7)*54 + (bid >> 3);  // bijection on [0,432)
  int h   = lin / 36;
  int idx = lin % 36;
  int qt = 0, rem = idx;
  while (rem > qt){ rem -= (qt+1); ++qt; }
  int ct = rem;                  // 0..qt
  int t0 = ct*64;

  int kvh  = h >> 1;
  int w    = threadIdx.x >> 6;
  int lane = threadIdx.x & 63;
  int lg   = lane >> 4;
  int lc   = lane & 15;

  // stage Q (f32, stride 68) + K (f32, XOR-swizzled cols)
  #pragma unroll
  for(int sub=0; sub<4; ++sub){
    int rr = w*16 + sub*4 + lg;
    int sw = ((lc ^ (rr>>2)) & 15)*4;
    *(float4*)&QPsh[rr*68 + lc*4] =
      *(const float4*)&qn[(size_t)(qt*64+rr)*CEMB + h*HD + lc*4];
    *(float4*)&Ksh[rr*64 + sw] =
      *(const float4*)&kn[(size_t)(t0+rr)*KVC + kvh*HD + lc*4];
  }
  // stage V transposed as bf16: VT[n][k], pack k-pairs (K1 B-staging idiom)
  {
    int kp = threadIdx.x >> 4;          // k-pair base 0..15
    int n4 = (threadIdx.x & 15)*4;
    #pragma unroll
    for(int half=0; half<2; ++half){
      int kk = (kp + half*16)*2;        // 0..62 even
      float4 v0 = *(const float4*)&vr[(size_t)(t0+kk  )*KVC + kvh*HD + n4];
      float4 v1 = *(const float4*)&vr[(size_t)(t0+kk+1)*KVC + kvh*HD + n4];
      #pragma unroll
      for(int i=0;i<4;i++)
        *(unsigned*)&VT[(n4+i)*72 + kk] = pack_bf16((&v0.x)[i], (&v1.x)[i]);
    }
  }
  __syncthreads();

  float s[4][4];
  #pragma unroll
  for(int r=0;r<4;r++)
    #pragma unroll
    for(int c=0;c<4;c++) s[r][c] = -INFINITY;

  #pragma unroll 4
  for(int dg=0; dg<16; ++dg){
    float4 k4[4], q4[4];
    int ksw = ((dg ^ lc)&15)*4;
    #pragma unroll
    for(int c=0;c<4;c++)
      k4[c] = *(const float4*)&Ksh[(lc*4+c)*64 + ksw];
    #pragma unroll
    for(int r=0;r<4;r++)
      q4[r] = *(const float4*)&QPsh[(w*16+lg*4+r)*68 + dg*4];
    #pragma unroll
    for(int r=0;r<4;r++)
      #pragma unroll
      for(int c=0;c<4;c++)
        s[r][c] = fmaxf(s[r][c],
                  fmaxf(fmaxf(q4[r].x + k4[c].x, q4[r].y + k4[c].y),
                        fmaxf(q4[r].z + k4[c].z, q4[r].w + k4[c].w)));
  }

  float mrow[4], lrow[4];
  #pragma unroll
  for(int r=0;r<4;r++){
    int i = qt*64 + w*16 + lg*4 + r;
    #pragma unroll
    for(int c=0;c<4;c++)
      if (t0 + lc*4 + c > i) s[r][c] = -INFINITY;   // causal mask
    float mt = fmaxf(fmaxf(s[r][0],s[r][1]), fmaxf(s[r][2],s[r][3]));
    mt = fmaxf(mt, __shfl_xor(mt,1));
    mt = fmaxf(mt, __shfl_xor(mt,2));
    mt = fmaxf(mt, __shfl_xor(mt,4));
    mt = fmaxf(mt, __shfl_xor(mt,8));
    float p0 = __expf(s[r][0]-mt), p1 = __expf(s[r][1]-mt);
    float p2 = __expf(s[r][2]-mt), p3 = __expf(s[r][3]-mt);
    float ps = p0+p1+p2+p3;
    ps += __shfl_xor(ps,1); ps += __shfl_xor(ps,2);
    ps += __shfl_xor(ps,4); ps += __shfl_xor(ps,8);
    mrow[r] = mt; lrow[r] = ps;
    int row = w*16 + lg*4 + r;
    *(unsigned*)&Pl[row*72 + lc*4]     = pack_bf16(p0,p1);
    *(unsigned*)&Pl[row*72 + lc*4 + 2] = pack_bf16(p2,p3);
    if (lc == 0) part_ml[(h*TT + i)*8 + ct] = make_float2(mrow[r], lrow[r]);
  }
  __builtin_amdgcn_wave_barrier();   // DS in-order per wave; P rows wave-private

  // PV via MFMA: wave w computes output rows w*16..w*16+15, all 64 cols.
  {
    int r_ = lane & 15, qq = lane >> 4;
    floatx4 pacc[4];
    #pragma unroll
    for(int c=0;c<4;c++) pacc[c] = (floatx4){0.f,0.f,0.f,0.f};

    short8 af0 = *(const short8*)&Pl[(w*16+r_)*72 + qq*8];
    short8 af1 = *(const short8*)&Pl[(w*16+r_)*72 + 32 + qq*8];
    #pragma unroll
    for(int c=0;c<4;c++){
      short8 b0 = *(const short8*)&VT[(c*16+r_)*72 + qq*8];
      short8 b1 = *(const short8*)&VT[(c*16+r_)*72 + 32 + qq*8];
      pacc[c] = __builtin_amdgcn_mfma_f32_16x16x32_bf16(af0, b0, pacc[c], 0,0,0);
      pacc[c] = __builtin_amdgcn_mfma_f32_16x16x32_bf16(af1, b1, pacc[c], 0,0,0);
    }

    #pragma unroll
    for(int reg=0; reg<4; ++reg){
      int i = qt*64 + w*16 + qq*4 + reg;
      size_t base = (size_t)((h*TT + i)*8 + ct)*64;
      #pragma unroll
      for(int c=0;c<4;c++)
        part_acc[base + c*16 + r_] = bf16_rn(pacc[c][reg]);
    }
  }
}

// ============================================================================
// K3: merge <=8 bf16 chunk partials per (h,row) -> yF bf16 A-fragments.
// (unchanged)
// ============================================================================
__global__ void __launch_bounds__(256) attn_reduce(const unsigned short* __restrict__ part_acc,
    const float2* __restrict__ part_ml, unsigned short* __restrict__ yF){
  int wid  = (blockIdx.x * blockDim.x + threadIdx.x) >> 6;  // 0..6143
  int lane = threadIdx.x & 63;
  int h = wid >> 9;
  int i = wid & 511;
  int nch = (i >> 6) + 1;       // wave-uniform
  int base = (h*TT + i)*8;

  float2 mls[8]; float acs[8];
  #pragma unroll
  for(int c=0;c<8;c++){
    mls[c] = part_ml[base + c];
    acs[c] = bf16_to_f32(part_acc[(size_t)(base + c)*64 + lane]);
  }

  float m = -INFINITY, l = 0.f, a = 0.f;
  #pragma unroll
  for(int c=0;c<8;c++){
    if (c < nch){
      float m_new = fmaxf(m, mls[c].x);
      float sa  = __expf(m - m_new);
      float sc_ = __expf(mls[c].x - m_new);
      l = l*sa + mls[c].y*sc_;
      a = a*sa + acs[c]*sc_;
      m = m_new;
    }
  }
  float val = a / l;
  int s = i>>4, rr = i&15;
  int ks = h*2 + (lane>>5), q2 = (lane>>3)&3, j = lane&7;
  yF[ (((size_t)(s*24 + ks)*64 + q2*16 + rr)<<3) + j ] = bf16_rn(val);
}

// ============================================================================
// K4: proj GEMM, fragment-direct, 192 blocks (8mt x 24 ntH of 32 cols).
// 4-deep rotating register prefetch, fully unrolled (compile-time indices).
// (unchanged)
// ============================================================================
__global__ void __launch_bounds__(256) gemm_proj_mfma(
    const unsigned short* __restrict__ yF, const unsigned short* __restrict__ WpF,
    float* __restrict__ out){
  int bx = blockIdx.x;           // 0..191
  int mt = bx / 24, ntH = bx % 24;
  int tid = threadIdx.x, w = tid>>6, lane = tid&63, qq = lane>>4, r = lane&15;
  int s = mt*4 + w;   // 16-row strip

  const short8* Af = (const short8*)yF  + (size_t)s*24*64 + lane;
  const short8* Bf = (const short8*)WpF + lane;

  floatx4 acc[2];
  acc[0] = (floatx4){0.f,0.f,0.f,0.f};
  acc[1] = (floatx4){0.f,0.f,0.f,0.f};

  short8 ar[4]; short8 br[4][2];
  #pragma unroll
  for(int j=0;j<3;++j){
    ar[j] = Af[(size_t)j*64];
    #pragma unroll
    for(int c=0;c<2;c++) br[j][c] = Bf[(size_t)((ntH*2+c)*24 + j)*64];
  }

  #pragma unroll
  for(int ks=0; ks<24; ++ks){
    int cur = ks & 3;
    if (ks + 3 < 24){
      int nx = (ks+3) & 3;
      ar[nx] = Af[(size_t)(ks+3)*64];
      #pragma unroll
      for(int c=0;c<2;c++) br[nx][c] = Bf[(size_t)((ntH*2+c)*24 + ks+3)*64];
    }
    #pragma unroll
    for(int c=0;c<2;c++)
      acc[c] = __builtin_amdgcn_mfma_f32_16x16x32_bf16(ar[cur], br[cur][c], acc[c], 0,0,0);
  }

  #pragma unroll
  for(int reg=0; reg<4; ++reg){
    int t = mt*64 + w*16 + qq*4 + reg;
    float* dst = out + (size_t)t*CEMB + ntH*32;
    #pragma unroll
    for(int c=0;c<2;c++)
      dst[c*16 + r] = acc[c][reg];
  }
}

extern "C" void kernel_launch(void* const* d_in, const int* in_sizes, int n_in,
                              void* d_out, int out_size, void* d_ws, size_t ws_size,
                              hipStream_t stream){
  const float* x    = (const float*)d_in[0];
  const float* cosb = (const float*)d_in[1];
  const float* sinb = (const float*)d_in[2];
  const float* Wq   = (const float*)d_in[3];
  const float* Wk   = (const float*)d_in[4];
  const float* Wv   = (const float*)d_in[5];
  const float* Wp   = (const float*)d_in[6];
  float* out = (float*)d_out;

  float* ws        = (float*)d_ws;
  float* q_raw     = ws;                                // 512*768 f32
  float* k_raw     = q_raw + (size_t)TT*CEMB;           // 512*384 f32
  float* v_raw     = k_raw + (size_t)TT*KVC;            // 512*384 f32
  unsigned short* part_acc = (unsigned short*)(v_raw + (size_t)TT*KVC); // 12*512*8*64 bf16
  float2* part_ml  = (float2*)(part_acc + (size_t)NH*TT*8*64);          // 12*512*8
  unsigned short* WpF = (unsigned short*)(part_ml + (size_t)NH*TT*8);   // 48*24*64*8
  unsigned short* yF  = WpF + (size_t)48*24*64*8;       // 32*24*64*8

  gemm_qkv_mfma <<<dim3(228),   256, 0, stream>>>(x, Wq, Wk, Wv, Wp, cosb, sinb,
                                                  q_raw, k_raw, v_raw, WpF);
  attn_tile     <<<dim3(432),   256, 0, stream>>>(q_raw, k_raw, v_raw, part_acc, part_ml);
  attn_reduce   <<<dim3(NH*TT/4), 256, 0, stream>>>(part_acc, part_ml, yF);
  gemm_proj_mfma<<<dim3(192),   256, 0, stream>>>(yF, WpF, out);
}